// Round 7
// baseline (273.533 us; speedup 1.0000x reference)
//
#include <hip/hip_runtime.h>

// Problem constants: B=1, C=128, H=96, W=128
#define K_TOT 128
#define H_DIM 96
#define W_DIM 128
#define M_TOT (H_DIM * W_DIM)   // 12288
#define N_TOT (H_DIM * W_DIM)   // 12288
#define SCALE 4
#define NEG_INF (-3.402823e38f)

#define KP 384                  // folded K' = 3 x 128 sections
#define NCH 12                  // K' chunks of 32

typedef _Float16 f16x8 __attribute__((ext_vector_type(8)));
typedef float f32x16 __attribute__((ext_vector_type(16)));

// async global->LDS, 16B/lane; LDS dest = wave-uniform base + lane*16
#define ASYNC16(lds_ptr, g_ptr) \
  __builtin_amdgcn_global_load_lds( \
      (const __attribute__((address_space(1))) unsigned int*)(g_ptr), \
      (__attribute__((address_space(3))) unsigned int*)(lds_ptr), 16, 0, 0)

// ---------------------------------------------------------------------------
// Prep: fp32 [K][P] -> f16 triplet rows [P][384], plus fused keys-init.
//  x = h + l/64 with h=f16(x), l=f16((x-hf)*64)  (x-hf exact by Sterbenz)
//  L rows: [h | h/64 | l]   R rows: [h | l | h/64]
//  => dot(A',B') = h*h' + h*(y-h') + (x-h)*h'  (drop (x-h)(y-h') ~ 2^-22|xy|)
// ---------------------------------------------------------------------------
__global__ __launch_bounds__(256)
void split_prep_kernel(const float* __restrict__ L, const float* __restrict__ R,
                       _Float16* __restrict__ Ls, _Float16* __restrict__ Rs,
                       unsigned long long* __restrict__ keys) {
    const int t = threadIdx.x;
    if (blockIdx.x >= 384) {            // fused keys init (48 blocks)
        int m = (blockIdx.x - 384) * 256 + t;
        if (m < M_TOT) keys[m] = 0ull;
        return;
    }
    __shared__ __align__(16) _Float16 T[3][64][136];   // planes: 0=h, 1=l, 2=h/64
    const int isR = blockIdx.x >= 192;
    const int P0 = (blockIdx.x - (isR ? 192 : 0)) * 64;
    const float* src = isR ? R : L;
    _Float16* dst = isR ? Rs : Ls;

    const int p4 = (t & 15) * 4;
    const int k0 = t >> 4;
#pragma unroll
    for (int it = 0; it < 8; ++it) {
        const int k = k0 + it * 16;
        float4 v = *(const float4*)&src[(size_t)k * M_TOT + P0 + p4];
        float xs[4] = {v.x, v.y, v.z, v.w};
#pragma unroll
        for (int j = 0; j < 4; ++j) {
            _Float16 h = (_Float16)xs[j];
            float hf = (float)h;
            float r = xs[j] - hf;                    // exact
            T[0][p4 + j][k] = h;
            T[1][p4 + j][k] = (_Float16)(r * 64.0f);
            T[2][p4 + j][k] = (_Float16)(hf * 0.015625f);  // h/64 (exact exp shift)
        }
    }
    __syncthreads();
    // write out: 64 rows x 48 chunks of 16B (8 f16). sec0=h, then per-side order.
#pragma unroll
    for (int it = 0; it < 12; ++it) {
        const int cid = it * 256 + t;
        const int row = cid / 48;
        const int seg = cid % 48;
        const int sec = seg >> 4;       // 0,1,2
        const int sub = seg & 15;
        const int plane = (sec == 0) ? 0 : (isR ? sec : 3 - sec);
        float4 v = *(const float4*)&T[plane][row][sub * 8];
        *(float4*)&dst[(size_t)(P0 + row) * KP + seg * 8] = v;
    }
}

// ---------------------------------------------------------------------------
// Main: 256x128 tile per 8-wave block; wave-tile 64x64; mfma_f32_32x32x16_f16;
// K'=384 in 12 chunks of 32, double-buffered LDS (48 KB), 1 barrier per chunk.
// launch_bounds(512,4) -> 2 blocks/CU = 16 waves/CU, no spill (acc = 64 regs).
// L2 supertiling: XCD x owns nt in [x*12, x*12+12) -> its 1.18 MB Rs slice is
// L2-resident for the whole kernel; Ls panels (196 KB) rotate slowly.
// LDS rows of 64B = 4 x 16B slots, slot XOR-swizzled by ((row>>1)&3);
// staging pre-swizzles the per-lane GLOBAL source (rule #21).
// ---------------------------------------------------------------------------
__global__ __launch_bounds__(512, 4)
void mfma_corr_kernel(const _Float16* __restrict__ Ls, const _Float16* __restrict__ Rs,
                      unsigned long long* __restrict__ keys) {
    __shared__ __align__(16) char smem[49152];   // A dbuf 2x16KB | B dbuf 2x8KB

    const int tid  = threadIdx.x;
    const int lane = tid & 63;
    const int wid  = tid >> 6;      // 0..7
    const int wr   = wid >> 1;      // 0..3 : M 64-row slab
    const int wc   = wid & 1;       // 0..1 : N 64-col slab
    // supertile swizzle: 4608 blocks = 8 XCDs x (48 mt x 12 nt_local)
    const int bid  = blockIdx.x;
    const int xcd  = bid & 7;
    const int b    = bid >> 3;              // 0..575
    const int mt   = b / 12;                // 0..47 (slow)
    const int nt   = xcd * 12 + b % 12;     // 0..95 (XCD-local slice)
    const int m0   = mt * 256;
    const int n0   = nt * 128;

    f32x16 acc[2][2];
#pragma unroll
    for (int mi = 0; mi < 2; ++mi)
#pragma unroll
        for (int ni = 0; ni < 2; ++ni) acc[mi][ni] = (f32x16)(0.0f);

    const int lr4  = lane >> 2;     // row within 16-row segment
    const int lsl  = lane & 3;      // physical slot
    const int col  = lane & 31;     // MFMA row/col lane index
    const int hi   = lane >> 5;     // k-half

    // stage one 32-f16 chunk of A(256 rows)+B(128 rows): 24 segs, 3 per wave
    auto stage = [&](int buf, int ch) {
#pragma unroll
        for (int i = 0; i < 3; ++i) {
            const int s  = wid * 3 + i;                 // 0..23
            const int ko = lsl;                         // slot before swizzle
            if (s < 16) {
                const int rl = s * 16 + lr4;            // A row 0..255
                const int kos = ko ^ ((rl >> 1) & 3);
                ASYNC16(smem + buf * 16384 + s * 1024,
                        Ls + (size_t)(m0 + rl) * KP + ch * 32 + kos * 8);
            } else {
                const int rl = (s - 16) * 16 + lr4;     // B row 0..127
                const int kos = ko ^ ((rl >> 1) & 3);
                ASYNC16(smem + 32768 + buf * 8192 + (s - 16) * 1024,
                        Rs + (size_t)(n0 + rl) * KP + ch * 32 + kos * 8);
            }
        }
    };

    stage(0, 0);
    __syncthreads();
    int cur = 0;
    for (int ch = 0; ch < NCH; ++ch) {
        if (ch + 1 < NCH) stage(cur ^ 1, ch + 1);   // prefetch next chunk
#pragma unroll
        for (int kk = 0; kk < 2; ++kk) {            // two K=16 halves of the chunk
            f16x8 a[2], b2[2];
#pragma unroll
            for (int mi = 0; mi < 2; ++mi) {
                const int rl = wr * 64 + mi * 32 + col;
                const int sl = (kk * 2 + hi) ^ ((rl >> 1) & 3);
                a[mi] = *(const f16x8*)(smem + cur * 16384 + rl * 64 + sl * 16);
            }
#pragma unroll
            for (int ni = 0; ni < 2; ++ni) {
                const int rl = wc * 64 + ni * 32 + col;
                const int sl = (kk * 2 + hi) ^ ((rl >> 1) & 3);
                b2[ni] = *(const f16x8*)(smem + 32768 + cur * 8192 + rl * 64 + sl * 16);
            }
#pragma unroll
            for (int mi = 0; mi < 2; ++mi)
#pragma unroll
                for (int ni = 0; ni < 2; ++ni)
                    acc[mi][ni] = __builtin_amdgcn_mfma_f32_32x32x16_f16(
                        a[mi], b2[ni], acc[mi][ni], 0, 0, 0);
        }
        __syncthreads();   // drains vmcnt(0): next buffer staged; LDS reads done
        cur ^= 1;
    }

    // --- epilogue ---
    // C/D 32x32 layout: col = lane&31, row = (reg&3) + 8*(reg>>2) + 4*(lane>>5)
    // ni-fold -> lane^16,^8 folds -> LDS [256][17] -> 256-thread row scan
    float* vals = (float*)smem;                    // 256*17*4 = 17408 B
    int*   idxs = (int*)(smem + 17408);            // 17408 B  (34816 < 49152)
#pragma unroll
    for (int mi = 0; mi < 2; ++mi) {
#pragma unroll
        for (int reg = 0; reg < 16; ++reg) {
            float best = acc[mi][0][reg];
            int bni = 0;
            if (acc[mi][1][reg] > best) { best = acc[mi][1][reg]; bni = 1; }
            int n = n0 + wc * 64 + bni * 32 + col;
#pragma unroll
            for (int d = 16; d >= 8; d >>= 1) {    // fold cols ^16 then ^8
                float ov = __shfl_xor(best, d, 64);
                int   oi = __shfl_xor(n, d, 64);
                if (ov > best || (ov == best && oi < n)) { best = ov; n = oi; }
            }
            if ((lane & 24) == 0) {
                const int row = wr * 64 + mi * 32 + (reg & 3) + 8 * (reg >> 2) + 4 * hi;
                const int c   = wc * 8 + (lane & 7);
                vals[row * 17 + c] = best;
                idxs[row * 17 + c] = n;
            }
        }
    }
    __syncthreads();
    if (tid < 256) {
        float bv = vals[tid * 17 + 0]; int bi = idxs[tid * 17 + 0];
#pragma unroll
        for (int c = 1; c < 16; ++c) {
            float v = vals[tid * 17 + c]; int ix = idxs[tid * 17 + c];
            if (v > bv || (v == bv && ix < bi)) { bv = v; bi = ix; }
        }
        unsigned vb = __float_as_uint(bv);
        vb = (vb & 0x80000000u) ? ~vb : (vb | 0x80000000u);
        unsigned long long key = ((unsigned long long)vb << 32) | (unsigned)(~bi);
        atomicMax(&keys[m0 + tid], key);
    }
}

// decode keys -> flow + cost
__global__ void finalize_keys_kernel(const unsigned long long* __restrict__ keys,
                                     float* __restrict__ out) {
    int m = blockIdx.x * blockDim.x + threadIdx.x;
    if (m >= M_TOT) return;
    unsigned long long key = keys[m];
    unsigned hi = (unsigned)(key >> 32);
    unsigned bits = (hi & 0x80000000u) ? (hi & 0x7fffffffu) : ~hi;
    float v = __uint_as_float(bits);
    int idx = (int)(~(unsigned)(key & 0xffffffffu));
    int h = m / W_DIM, w = m % W_DIM;
    int i = idx / W_DIM, j = idx % W_DIM;
    out[m * 2 + 0] = (float)(w - SCALE * j);
    out[m * 2 + 1] = (float)(h - SCALE * i);
    out[2 * M_TOT + m] = v;
}

// ---------------------------------------------------------------------------
// Fallback fp32 VALU path in case ws_size is too small.
// ---------------------------------------------------------------------------
#define BM 128
#define BN 128
#define KB 32
__global__ __launch_bounds__(256)
void corr_argmax_kernel(const float* __restrict__ L, const float* __restrict__ R,
                        float* __restrict__ pbest, int* __restrict__ pidx,
                        int nsplit) {
    __shared__ float As[KB][BM];
    __shared__ float Bs[KB][BN];
    const int tid = threadIdx.x;
    const int mtiles = M_TOT / BM;
    const int mt = blockIdx.x % mtiles;
    const int s  = blockIdx.x / mtiles;
    const int m0 = mt * BM;
    const int ns = N_TOT / nsplit;
    const int ntiles = ns / BN;
    const int tx = tid & 15;
    const int ty = tid >> 4;
    float rbest[8]; int ridx[8];
#pragma unroll
    for (int i = 0; i < 8; ++i) { rbest[i] = NEG_INF; ridx[i] = 0; }
    for (int nt = 0; nt < ntiles; ++nt) {
        const int n0 = s * ns + nt * BN;
        float acc[8][8];
#pragma unroll
        for (int i = 0; i < 8; ++i)
#pragma unroll
            for (int j = 0; j < 8; ++j) acc[i][j] = 0.f;
        for (int kb = 0; kb < K_TOT; kb += KB) {
            __syncthreads();
#pragma unroll
            for (int r = 0; r < 4; ++r) {
                int f  = tid + 256 * r;
                int kk = f >> 5;
                int c4 = f & 31;
                float4 va = *reinterpret_cast<const float4*>(&L[(size_t)(kb + kk) * M_TOT + m0 + c4 * 4]);
                *reinterpret_cast<float4*>(&As[kk][c4 * 4]) = va;
                float4 vb = *reinterpret_cast<const float4*>(&R[(size_t)(kb + kk) * N_TOT + n0 + c4 * 4]);
                *reinterpret_cast<float4*>(&Bs[kk][c4 * 4]) = vb;
            }
            __syncthreads();
#pragma unroll 4
            for (int kk = 0; kk < KB; ++kk) {
                float4 a0 = *reinterpret_cast<const float4*>(&As[kk][ty * 4]);
                float4 a1 = *reinterpret_cast<const float4*>(&As[kk][64 + ty * 4]);
                float4 b0 = *reinterpret_cast<const float4*>(&Bs[kk][tx * 4]);
                float4 b1 = *reinterpret_cast<const float4*>(&Bs[kk][64 + tx * 4]);
                float a[8] = {a0.x, a0.y, a0.z, a0.w, a1.x, a1.y, a1.z, a1.w};
                float b[8] = {b0.x, b0.y, b0.z, b0.w, b1.x, b1.y, b1.z, b1.w};
#pragma unroll
                for (int i = 0; i < 8; ++i)
#pragma unroll
                    for (int j = 0; j < 8; ++j)
                        acc[i][j] = fmaf(a[i], b[j], acc[i][j]);
            }
        }
#pragma unroll
        for (int i = 0; i < 8; ++i)
#pragma unroll
            for (int jh = 0; jh < 2; ++jh)
#pragma unroll
                for (int jj = 0; jj < 4; ++jj) {
                    int n = n0 + jh * 64 + tx * 4 + jj;
                    float v = acc[i][jh * 4 + jj];
                    if (v > rbest[i]) { rbest[i] = v; ridx[i] = n; }
                }
    }
    __syncthreads();
    float (*redv)[BM] = reinterpret_cast<float(*)[BM]>(&As[0][0]);
    int   (*redi)[BM] = reinterpret_cast<int  (*)[BM]>(&Bs[0][0]);
#pragma unroll
    for (int i = 0; i < 8; ++i) {
        int row = (i >> 2) * 64 + ty * 4 + (i & 3);
        redv[tx][row] = rbest[i];
        redi[tx][row] = ridx[i];
    }
    __syncthreads();
    if (tid < BM) {
        float bv = NEG_INF; int bi = 0x7fffffff;
        for (int t = 0; t < 16; ++t) {
            float v  = redv[t][tid];
            int   ix = redi[t][tid];
            if (v > bv || (v == bv && ix < bi)) { bv = v; bi = ix; }
        }
        pbest[(size_t)s * M_TOT + m0 + tid] = bv;
        pidx [(size_t)s * M_TOT + m0 + tid] = bi;
    }
}

__global__ void finalize_parts_kernel(const float* __restrict__ pbest,
                                      const int* __restrict__ pidx,
                                      float* __restrict__ out, int nsplit) {
    int m = blockIdx.x * blockDim.x + threadIdx.x;
    if (m >= M_TOT) return;
    float bv = NEG_INF; int bi = 0x7fffffff;
    for (int s = 0; s < nsplit; ++s) {
        float v  = pbest[(size_t)s * M_TOT + m];
        int   ix = pidx [(size_t)s * M_TOT + m];
        if (v > bv || (v == bv && ix < bi)) { bv = v; bi = ix; }
    }
    int h = m / W_DIM, w = m % W_DIM;
    int i = bi / W_DIM, j = bi % W_DIM;
    out[m * 2 + 0] = (float)(w - SCALE * j);
    out[m * 2 + 1] = (float)(h - SCALE * i);
    out[2 * M_TOT + m] = bv;
}

extern "C" void kernel_launch(void* const* d_in, const int* in_sizes, int n_in,
                              void* d_out, int out_size, void* d_ws, size_t ws_size,
                              hipStream_t stream) {
    const float* L = (const float*)d_in[0];
    const float* R = (const float*)d_in[1];
    float* out = (float*)d_out;

    const size_t PKbytes = (size_t)M_TOT * KP * sizeof(_Float16);   // 9.44 MB
    const size_t need = 2 * PKbytes + (size_t)M_TOT * 8;            // ~19 MB
    if (ws_size >= need) {
        _Float16* Ls = (_Float16*)d_ws;
        _Float16* Rs = (_Float16*)((char*)d_ws + PKbytes);
        unsigned long long* keys = (unsigned long long*)((char*)d_ws + 2 * PKbytes);
        split_prep_kernel<<<dim3(432), dim3(256), 0, stream>>>(L, R, Ls, Rs, keys);
        mfma_corr_kernel<<<dim3((M_TOT / 256) * (N_TOT / 128)), dim3(512), 0, stream>>>(Ls, Rs, keys);
        finalize_keys_kernel<<<dim3(48), dim3(256), 0, stream>>>(keys, out);
    } else {
        int nsplit = 8;
        while (nsplit > 1 && (size_t)nsplit * M_TOT * 8 > ws_size) nsplit >>= 1;
        float* pbest = (float*)d_ws;
        int*   pidx  = (int*)((char*)d_ws + (size_t)nsplit * M_TOT * sizeof(float));
        corr_argmax_kernel<<<dim3((M_TOT / BM) * nsplit), dim3(256), 0, stream>>>(L, R, pbest, pidx, nsplit);
        finalize_parts_kernel<<<dim3((M_TOT + 255) / 256), dim3(256), 0, stream>>>(pbest, pidx, out, nsplit);
    }
}

// Round 8
// 265.838 us; speedup vs baseline: 1.0289x; 1.0289x over previous
//
#include <hip/hip_runtime.h>

// Problem constants: B=1, C=128, H=96, W=128
#define K_TOT 128
#define H_DIM 96
#define W_DIM 128
#define M_TOT (H_DIM * W_DIM)   // 12288
#define N_TOT (H_DIM * W_DIM)   // 12288
#define SCALE 4
#define NEG_INF (-3.402823e38f)

#define KP 384                  // folded K' = 3 x 128 sections
#define NCH 12                  // K' chunks of 32

typedef _Float16 f16x8 __attribute__((ext_vector_type(8)));
typedef float f32x16 __attribute__((ext_vector_type(16)));

// async global->LDS, 16B/lane; LDS dest = wave-uniform base + lane*16
#define ASYNC16(lds_ptr, g_ptr) \
  __builtin_amdgcn_global_load_lds( \
      (const __attribute__((address_space(1))) unsigned int*)(g_ptr), \
      (__attribute__((address_space(3))) unsigned int*)(lds_ptr), 16, 0, 0)

// ---------------------------------------------------------------------------
// Prep: fp32 [K][P] -> f16 triplet rows [P][384], plus fused keys-init.
//  x = h + l/64 with h=f16(x), l=f16((x-hf)*64)  (x-hf exact by Sterbenz)
//  L rows: [h | h/64 | l]   R rows: [h | l | h/64]
//  => dot(A',B') = h*h' + h*(y-h') + (x-h)*h'  (drop (x-h)(y-h') ~ 2^-22|xy|)
// ---------------------------------------------------------------------------
__global__ __launch_bounds__(256)
void split_prep_kernel(const float* __restrict__ L, const float* __restrict__ R,
                       _Float16* __restrict__ Ls, _Float16* __restrict__ Rs,
                       unsigned long long* __restrict__ keys) {
    const int t = threadIdx.x;
    if (blockIdx.x >= 384) {            // fused keys init (48 blocks)
        int m = (blockIdx.x - 384) * 256 + t;
        if (m < M_TOT) keys[m] = 0ull;
        return;
    }
    __shared__ __align__(16) _Float16 T[3][64][136];   // planes: 0=h, 1=l, 2=h/64
    const int isR = blockIdx.x >= 192;
    const int P0 = (blockIdx.x - (isR ? 192 : 0)) * 64;
    const float* src = isR ? R : L;
    _Float16* dst = isR ? Rs : Ls;

    const int p4 = (t & 15) * 4;
    const int k0 = t >> 4;
#pragma unroll
    for (int it = 0; it < 8; ++it) {
        const int k = k0 + it * 16;
        float4 v = *(const float4*)&src[(size_t)k * M_TOT + P0 + p4];
        float xs[4] = {v.x, v.y, v.z, v.w};
#pragma unroll
        for (int j = 0; j < 4; ++j) {
            _Float16 h = (_Float16)xs[j];
            float hf = (float)h;
            float r = xs[j] - hf;                    // exact
            T[0][p4 + j][k] = h;
            T[1][p4 + j][k] = (_Float16)(r * 64.0f);
            T[2][p4 + j][k] = (_Float16)(hf * 0.015625f);  // h/64 (exact exp shift)
        }
    }
    __syncthreads();
    // write out: 64 rows x 48 chunks of 16B (8 f16). sec0=h, then per-side order.
#pragma unroll
    for (int it = 0; it < 12; ++it) {
        const int cid = it * 256 + t;
        const int row = cid / 48;
        const int seg = cid % 48;
        const int sec = seg >> 4;       // 0,1,2
        const int sub = seg & 15;
        const int plane = (sec == 0) ? 0 : (isR ? sec : 3 - sec);
        float4 v = *(const float4*)&T[plane][row][sub * 8];
        *(float4*)&dst[(size_t)(P0 + row) * KP + seg * 8] = v;
    }
}

// ---------------------------------------------------------------------------
// Main: 256x128 tile per 8-wave block; wave-tile 64x64; mfma_f32_32x32x16_f16;
// K'=384 in 12 chunks of 32. TRIPLE-buffered LDS (72 KB), depth-2 prefetch,
// counted vmcnt (never 0 in steady state) + raw s_barrier: one barrier/chunk,
// stage(ch) has ~2 chunk-times to land (T3+T4 minimum form). T5 setprio
// around the MFMA cluster. 2 blocks/CU (LDS-limited), 16 waves/CU.
// L2 supertiling: XCD x owns nt in [x*12, x*12+12) -> 1.18 MB Rs slice
// L2-resident; Ls panels (196 KB) rotate slowly.
// vmcnt derivation: 3 loads/wave/stage, 2 stages in flight -> wait vmcnt(3)
// = oldest stage landed; barrier then makes it landed for ALL waves.
// stage(ch+2) overwrites buf[(ch-1)%3]: its readers passed this chunk's
// barrier already (MFMA lgkm-consumed) => safe.
// ---------------------------------------------------------------------------
__global__ __launch_bounds__(512, 4)
void mfma_corr_kernel(const _Float16* __restrict__ Ls, const _Float16* __restrict__ Rs,
                      unsigned long long* __restrict__ keys) {
    __shared__ __align__(16) char smem[73728];   // A: 3x16KB @0 | B: 3x8KB @49152

    const int tid  = threadIdx.x;
    const int lane = tid & 63;
    const int wid  = tid >> 6;      // 0..7
    const int wr   = wid >> 1;      // 0..3 : M 64-row slab
    const int wc   = wid & 1;       // 0..1 : N 64-col slab
    // supertile swizzle: 4608 blocks = 8 XCDs x (48 mt x 12 nt_local)
    const int bid  = blockIdx.x;
    const int xcd  = bid & 7;
    const int b    = bid >> 3;              // 0..575
    const int mt   = b / 12;                // 0..47 (slow)
    const int nt   = xcd * 12 + b % 12;     // 0..95 (XCD-local slice)
    const int m0   = mt * 256;
    const int n0   = nt * 128;

    f32x16 acc[2][2];
#pragma unroll
    for (int mi = 0; mi < 2; ++mi)
#pragma unroll
        for (int ni = 0; ni < 2; ++ni) acc[mi][ni] = (f32x16)(0.0f);

    const int lr4  = lane >> 2;     // row within 16-row segment
    const int lsl  = lane & 3;      // physical slot
    const int col  = lane & 31;     // MFMA row/col lane index
    const int hi   = lane >> 5;     // k-half

    // stage one 32-f16 chunk of A(256 rows)+B(128 rows): 24 segs, 3 per wave
    auto stage = [&](int buf, int ch) {
#pragma unroll
        for (int i = 0; i < 3; ++i) {
            const int s = wid * 3 + i;                  // 0..23
            if (s < 16) {
                const int rl  = s * 16 + lr4;           // A row 0..255
                const int kos = lsl ^ ((rl >> 1) & 3);  // pre-swizzled source slot
                ASYNC16(smem + buf * 16384 + s * 1024,
                        Ls + (size_t)(m0 + rl) * KP + ch * 32 + kos * 8);
            } else {
                const int rl  = (s - 16) * 16 + lr4;    // B row 0..127
                const int kos = lsl ^ ((rl >> 1) & 3);
                ASYNC16(smem + 49152 + buf * 8192 + (s - 16) * 1024,
                        Rs + (size_t)(n0 + rl) * KP + ch * 32 + kos * 8);
            }
        }
    };

    auto compute = [&](int cb) {
#pragma unroll
        for (int kk = 0; kk < 2; ++kk) {            // two K=16 halves of the chunk
            f16x8 a[2], b2[2];
#pragma unroll
            for (int mi = 0; mi < 2; ++mi) {
                const int rl = wr * 64 + mi * 32 + col;
                const int sl = (kk * 2 + hi) ^ ((rl >> 1) & 3);
                a[mi] = *(const f16x8*)(smem + cb * 16384 + rl * 64 + sl * 16);
            }
#pragma unroll
            for (int ni = 0; ni < 2; ++ni) {
                const int rl = wc * 64 + ni * 32 + col;
                const int sl = (kk * 2 + hi) ^ ((rl >> 1) & 3);
                b2[ni] = *(const f16x8*)(smem + 49152 + cb * 8192 + rl * 64 + sl * 16);
            }
            __builtin_amdgcn_s_setprio(1);
#pragma unroll
            for (int mi = 0; mi < 2; ++mi)
#pragma unroll
                for (int ni = 0; ni < 2; ++ni)
                    acc[mi][ni] = __builtin_amdgcn_mfma_f32_32x32x16_f16(
                        a[mi], b2[ni], acc[mi][ni], 0, 0, 0);
            __builtin_amdgcn_s_setprio(0);
        }
    };

    stage(0, 0);
    stage(1, 1);                    // 6 loads outstanding per wave
    for (int ch = 0; ch < NCH - 1; ++ch) {
        asm volatile("s_waitcnt vmcnt(3)" ::: "memory");   // stage(ch) landed (own)
        __builtin_amdgcn_s_barrier();                      // landed for all waves
        if (ch + 2 < NCH) stage((ch + 2) % 3, ch + 2);     // back to <=6 in flight
        compute(ch % 3);
    }
    asm volatile("s_waitcnt vmcnt(0)" ::: "memory");       // last stage landed
    __builtin_amdgcn_s_barrier();
    compute((NCH - 1) % 3);

    // --- epilogue ---
    __syncthreads();   // all LDS reads done before smem reuse
    // C/D 32x32 layout: col = lane&31, row = (reg&3) + 8*(reg>>2) + 4*(lane>>5)
    // ni-fold -> lane^16,^8 folds -> LDS [256][17] -> 256-thread row scan
    float* vals = (float*)smem;                    // 256*17*4 = 17408 B
    int*   idxs = (int*)(smem + 17408);            // 17408 B  (34816 < 73728)
#pragma unroll
    for (int mi = 0; mi < 2; ++mi) {
#pragma unroll
        for (int reg = 0; reg < 16; ++reg) {
            float best = acc[mi][0][reg];
            int bni = 0;
            if (acc[mi][1][reg] > best) { best = acc[mi][1][reg]; bni = 1; }
            int n = n0 + wc * 64 + bni * 32 + col;
#pragma unroll
            for (int d = 16; d >= 8; d >>= 1) {    // fold cols ^16 then ^8
                float ov = __shfl_xor(best, d, 64);
                int   oi = __shfl_xor(n, d, 64);
                if (ov > best || (ov == best && oi < n)) { best = ov; n = oi; }
            }
            if ((lane & 24) == 0) {
                const int row = wr * 64 + mi * 32 + (reg & 3) + 8 * (reg >> 2) + 4 * hi;
                const int c   = wc * 8 + (lane & 7);
                vals[row * 17 + c] = best;
                idxs[row * 17 + c] = n;
            }
        }
    }
    __syncthreads();
    if (tid < 256) {
        float bv = vals[tid * 17 + 0]; int bi = idxs[tid * 17 + 0];
#pragma unroll
        for (int c = 1; c < 16; ++c) {
            float v = vals[tid * 17 + c]; int ix = idxs[tid * 17 + c];
            if (v > bv || (v == bv && ix < bi)) { bv = v; bi = ix; }
        }
        unsigned vb = __float_as_uint(bv);
        vb = (vb & 0x80000000u) ? ~vb : (vb | 0x80000000u);
        unsigned long long key = ((unsigned long long)vb << 32) | (unsigned)(~bi);
        atomicMax(&keys[m0 + tid], key);
    }
}

// decode keys -> flow + cost
__global__ void finalize_keys_kernel(const unsigned long long* __restrict__ keys,
                                     float* __restrict__ out) {
    int m = blockIdx.x * blockDim.x + threadIdx.x;
    if (m >= M_TOT) return;
    unsigned long long key = keys[m];
    unsigned hi = (unsigned)(key >> 32);
    unsigned bits = (hi & 0x80000000u) ? (hi & 0x7fffffffu) : ~hi;
    float v = __uint_as_float(bits);
    int idx = (int)(~(unsigned)(key & 0xffffffffu));
    int h = m / W_DIM, w = m % W_DIM;
    int i = idx / W_DIM, j = idx % W_DIM;
    out[m * 2 + 0] = (float)(w - SCALE * j);
    out[m * 2 + 1] = (float)(h - SCALE * i);
    out[2 * M_TOT + m] = v;
}

// ---------------------------------------------------------------------------
// Fallback fp32 VALU path in case ws_size is too small.
// ---------------------------------------------------------------------------
#define BM 128
#define BN 128
#define KB 32
__global__ __launch_bounds__(256)
void corr_argmax_kernel(const float* __restrict__ L, const float* __restrict__ R,
                        float* __restrict__ pbest, int* __restrict__ pidx,
                        int nsplit) {
    __shared__ float As[KB][BM];
    __shared__ float Bs[KB][BN];
    const int tid = threadIdx.x;
    const int mtiles = M_TOT / BM;
    const int mt = blockIdx.x % mtiles;
    const int s  = blockIdx.x / mtiles;
    const int m0 = mt * BM;
    const int ns = N_TOT / nsplit;
    const int ntiles = ns / BN;
    const int tx = tid & 15;
    const int ty = tid >> 4;
    float rbest[8]; int ridx[8];
#pragma unroll
    for (int i = 0; i < 8; ++i) { rbest[i] = NEG_INF; ridx[i] = 0; }
    for (int nt = 0; nt < ntiles; ++nt) {
        const int n0 = s * ns + nt * BN;
        float acc[8][8];
#pragma unroll
        for (int i = 0; i < 8; ++i)
#pragma unroll
            for (int j = 0; j < 8; ++j) acc[i][j] = 0.f;
        for (int kb = 0; kb < K_TOT; kb += KB) {
            __syncthreads();
#pragma unroll
            for (int r = 0; r < 4; ++r) {
                int f  = tid + 256 * r;
                int kk = f >> 5;
                int c4 = f & 31;
                float4 va = *reinterpret_cast<const float4*>(&L[(size_t)(kb + kk) * M_TOT + m0 + c4 * 4]);
                *reinterpret_cast<float4*>(&As[kk][c4 * 4]) = va;
                float4 vb = *reinterpret_cast<const float4*>(&R[(size_t)(kb + kk) * N_TOT + n0 + c4 * 4]);
                *reinterpret_cast<float4*>(&Bs[kk][c4 * 4]) = vb;
            }
            __syncthreads();
#pragma unroll 4
            for (int kk = 0; kk < KB; ++kk) {
                float4 a0 = *reinterpret_cast<const float4*>(&As[kk][ty * 4]);
                float4 a1 = *reinterpret_cast<const float4*>(&As[kk][64 + ty * 4]);
                float4 b0 = *reinterpret_cast<const float4*>(&Bs[kk][tx * 4]);
                float4 b1 = *reinterpret_cast<const float4*>(&Bs[kk][64 + tx * 4]);
                float a[8] = {a0.x, a0.y, a0.z, a0.w, a1.x, a1.y, a1.z, a1.w};
                float b[8] = {b0.x, b0.y, b0.z, b0.w, b1.x, b1.y, b1.z, b1.w};
#pragma unroll
                for (int i = 0; i < 8; ++i)
#pragma unroll
                    for (int j = 0; j < 8; ++j)
                        acc[i][j] = fmaf(a[i], b[j], acc[i][j]);
            }
        }
#pragma unroll
        for (int i = 0; i < 8; ++i)
#pragma unroll
            for (int jh = 0; jh < 2; ++jh)
#pragma unroll
                for (int jj = 0; jj < 4; ++jj) {
                    int n = n0 + jh * 64 + tx * 4 + jj;
                    float v = acc[i][jh * 4 + jj];
                    if (v > rbest[i]) { rbest[i] = v; ridx[i] = n; }
                }
    }
    __syncthreads();
    float (*redv)[BM] = reinterpret_cast<float(*)[BM]>(&As[0][0]);
    int   (*redi)[BM] = reinterpret_cast<int  (*)[BM]>(&Bs[0][0]);
#pragma unroll
    for (int i = 0; i < 8; ++i) {
        int row = (i >> 2) * 64 + ty * 4 + (i & 3);
        redv[tx][row] = rbest[i];
        redi[tx][row] = ridx[i];
    }
    __syncthreads();
    if (tid < BM) {
        float bv = NEG_INF; int bi = 0x7fffffff;
        for (int t = 0; t < 16; ++t) {
            float v  = redv[t][tid];
            int   ix = redi[t][tid];
            if (v > bv || (v == bv && ix < bi)) { bv = v; bi = ix; }
        }
        pbest[(size_t)s * M_TOT + m0 + tid] = bv;
        pidx [(size_t)s * M_TOT + m0 + tid] = bi;
    }
}

__global__ void finalize_parts_kernel(const float* __restrict__ pbest,
                                      const int* __restrict__ pidx,
                                      float* __restrict__ out, int nsplit) {
    int m = blockIdx.x * blockDim.x + threadIdx.x;
    if (m >= M_TOT) return;
    float bv = NEG_INF; int bi = 0x7fffffff;
    for (int s = 0; s < nsplit; ++s) {
        float v  = pbest[(size_t)s * M_TOT + m];
        int   ix = pidx [(size_t)s * M_TOT + m];
        if (v > bv || (v == bv && ix < bi)) { bv = v; bi = ix; }
    }
    int h = m / W_DIM, w = m % W_DIM;
    int i = bi / W_DIM, j = bi % W_DIM;
    out[m * 2 + 0] = (float)(w - SCALE * j);
    out[m * 2 + 1] = (float)(h - SCALE * i);
    out[2 * M_TOT + m] = bv;
}

extern "C" void kernel_launch(void* const* d_in, const int* in_sizes, int n_in,
                              void* d_out, int out_size, void* d_ws, size_t ws_size,
                              hipStream_t stream) {
    const float* L = (const float*)d_in[0];
    const float* R = (const float*)d_in[1];
    float* out = (float*)d_out;

    const size_t PKbytes = (size_t)M_TOT * KP * sizeof(_Float16);   // 9.44 MB
    const size_t need = 2 * PKbytes + (size_t)M_TOT * 8;            // ~19 MB
    if (ws_size >= need) {
        _Float16* Ls = (_Float16*)d_ws;
        _Float16* Rs = (_Float16*)((char*)d_ws + PKbytes);
        unsigned long long* keys = (unsigned long long*)((char*)d_ws + 2 * PKbytes);
        split_prep_kernel<<<dim3(432), dim3(256), 0, stream>>>(L, R, Ls, Rs, keys);
        mfma_corr_kernel<<<dim3((M_TOT / 256) * (N_TOT / 128)), dim3(512), 0, stream>>>(Ls, Rs, keys);
        finalize_keys_kernel<<<dim3(48), dim3(256), 0, stream>>>(keys, out);
    } else {
        int nsplit = 8;
        while (nsplit > 1 && (size_t)nsplit * M_TOT * 8 > ws_size) nsplit >>= 1;
        float* pbest = (float*)d_ws;
        int*   pidx  = (int*)((char*)d_ws + (size_t)nsplit * M_TOT * sizeof(float));
        corr_argmax_kernel<<<dim3((M_TOT / BM) * nsplit), dim3(256), 0, stream>>>(L, R, pbest, pidx, nsplit);
        finalize_parts_kernel<<<dim3((M_TOT + 255) / 256), dim3(256), 0, stream>>>(pbest, pidx, out, nsplit);
    }
}

// Round 9
// 259.209 us; speedup vs baseline: 1.0553x; 1.0256x over previous
//
#include <hip/hip_runtime.h>

// Problem constants: B=1, C=128, H=96, W=128
#define K_TOT 128
#define H_DIM 96
#define W_DIM 128
#define M_TOT (H_DIM * W_DIM)   // 12288
#define N_TOT (H_DIM * W_DIM)   // 12288
#define SCALE 4
#define NEG_INF (-3.402823e38f)

#define KP 384                  // folded K' = 3 x 128 sections
#define NH 24                   // K' halves of 16
#define SLAB_F16 24576          // 64 rows x 384 k' f16 per slab

typedef _Float16 f16x8 __attribute__((ext_vector_type(8)));
typedef float f32x16 __attribute__((ext_vector_type(16)));

// ---------------------------------------------------------------------------
// Prep: fp32 [K][P] -> f16 triplet in FRAG-MAJOR layout + fused keys-init.
//  x = h + l/64 with h=f16(x), l=f16((x-hf)*64)  (x-hf exact by Sterbenz)
//  k' sections: L: [h | h/64 | l]   R: [h | l | h/64]
//  => dot = h*h' + h*(y-h') + (x-h)*h'  (drop (x-h)(y-h') ~ 2^-22|xy|)
// Frag-major: slab s (64 rows), chunk c = half*128 + op*64 + hi*32 + col
// (half=k'/16, op=32-row half, hi=k-half, col=row%32): 8 f16 at
// dst[s*24576 + c*8] = exactly lane (hi*32+col)'s MFMA operand bytes.
// A wave's frag load is then one coalesced 1024B global_load_dwordx4 sweep.
// ---------------------------------------------------------------------------
__global__ __launch_bounds__(256)
void split_prep_kernel(const float* __restrict__ L, const float* __restrict__ R,
                       _Float16* __restrict__ Ls, _Float16* __restrict__ Rs,
                       unsigned long long* __restrict__ keys) {
    const int t = threadIdx.x;
    if (blockIdx.x >= 384) {            // fused keys init (48 blocks)
        int m = (blockIdx.x - 384) * 256 + t;
        if (m < M_TOT) keys[m] = 0ull;
        return;
    }
    __shared__ __align__(16) _Float16 T[3][64][144];   // planes: 0=h, 1=l, 2=h/64
    const int isR  = blockIdx.x >= 192;
    const int slab = blockIdx.x - (isR ? 192 : 0);     // 0..191
    const int P0   = slab * 64;
    const float* src = isR ? R : L;
    _Float16* dst = isR ? Rs : Ls;

    const int p4 = (t & 15) * 4;
    const int k0 = t >> 4;
#pragma unroll
    for (int it = 0; it < 8; ++it) {
        const int k = k0 + it * 16;
        float4 v = *(const float4*)&src[(size_t)k * M_TOT + P0 + p4];
        float xs[4] = {v.x, v.y, v.z, v.w};
#pragma unroll
        for (int j = 0; j < 4; ++j) {
            _Float16 h = (_Float16)xs[j];
            float hf = (float)h;
            float r = xs[j] - hf;                    // exact
            T[0][p4 + j][k] = h;
            T[1][p4 + j][k] = (_Float16)(r * 64.0f);
            T[2][p4 + j][k] = (_Float16)(hf * 0.015625f);  // h/64 (exact exp shift)
        }
    }
    __syncthreads();
    // 3072 16B-chunks per slab: c = half*128 + op*64 + hi*32 + col
#pragma unroll
    for (int it = 0; it < 12; ++it) {
        const int c    = it * 256 + t;
        const int col  = c & 31;
        const int hi   = (c >> 5) & 1;
        const int op   = (c >> 6) & 1;
        const int half = c >> 7;             // 0..23
        const int sec  = half >> 3;          // 0,1,2
        const int kb   = (half & 7) * 16 + hi * 8;
        const int plane = (sec == 0) ? 0 : (isR ? sec : 3 - sec);
        const int row  = op * 32 + col;
        float4 v = *(const float4*)&T[plane][row][kb];
        *(float4*)&dst[(size_t)slab * SLAB_F16 + (size_t)c * 8] = v;
    }
}

// ---------------------------------------------------------------------------
// Main: 128x128 tile, 4 waves (2x2), wave-tile 64x64, mfma_f32_32x32x16_f16.
// NO LDS / NO barriers in the K loop: fragments load directly global->VGPR
// from the frag-major workspace (coalesced 1024B per wave-frag), register
// triple-buffer with depth-2 prefetch (static %3 indices under full unroll);
// the compiler inserts the counted vmcnt before first use. Reuse lives in
// L2: XCD supertile keeps each XCD's 1.15 MB B slice resident.
// 12 waves/CU (launch_bounds(256,3)); epilogue uses a small LDS reduce.
// ---------------------------------------------------------------------------
__global__ __launch_bounds__(256, 3)
void mfma_corr_kernel(const _Float16* __restrict__ Ls, const _Float16* __restrict__ Rs,
                      unsigned long long* __restrict__ keys) {
    __shared__ float vals[128 * 17];
    __shared__ int   idxs[128 * 17];

    const int tid  = threadIdx.x;
    const int lane = tid & 63;
    const int wid  = tid >> 6;      // 0..3
    const int wr   = wid >> 1;      // 0..1 : M 64-row slab
    const int wc   = wid & 1;       // 0..1 : N 64-col slab
    const int col  = lane & 31;
    const int hi   = lane >> 5;
    // supertile: 9216 = 8 XCDs x (96 mt x 12 nt_local); bijective
    const int bid  = blockIdx.x;
    const int xcd  = bid & 7;
    const int b    = bid >> 3;              // 0..1151
    const int mt   = b / 12;                // 0..95 (slow)
    const int nt   = xcd * 12 + b % 12;     // 0..95 (XCD-local slice)
    const int m0   = mt * 128;
    const int n0   = nt * 128;

    const _Float16* pA = Ls + (size_t)(mt * 2 + wr) * SLAB_F16 + lane * 8;
    const _Float16* pB = Rs + (size_t)(nt * 2 + wc) * SLAB_F16 + lane * 8;

    f32x16 acc[2][2];
#pragma unroll
    for (int mi = 0; mi < 2; ++mi)
#pragma unroll
        for (int ni = 0; ni < 2; ++ni) acc[mi][ni] = (f32x16)(0.0f);

    f16x8 fA[3][2], fB[3][2];
#define LOADH(hh, s) {                                              \
        fA[s][0] = *(const f16x8*)(pA + (hh) * 1024);               \
        fA[s][1] = *(const f16x8*)(pA + (hh) * 1024 + 512);         \
        fB[s][0] = *(const f16x8*)(pB + (hh) * 1024);               \
        fB[s][1] = *(const f16x8*)(pB + (hh) * 1024 + 512);         \
    }
    LOADH(0, 0);
    LOADH(1, 1);
#pragma unroll
    for (int h = 0; h < NH; ++h) {
        if (h + 2 < NH) LOADH(h + 2, (h + 2) % 3);      // depth-2 prefetch
        const int s = h % 3;                             // static under unroll
        acc[0][0] = __builtin_amdgcn_mfma_f32_32x32x16_f16(fA[s][0], fB[s][0], acc[0][0], 0, 0, 0);
        acc[0][1] = __builtin_amdgcn_mfma_f32_32x32x16_f16(fA[s][0], fB[s][1], acc[0][1], 0, 0, 0);
        acc[1][0] = __builtin_amdgcn_mfma_f32_32x32x16_f16(fA[s][1], fB[s][0], acc[1][0], 0, 0, 0);
        acc[1][1] = __builtin_amdgcn_mfma_f32_32x32x16_f16(fA[s][1], fB[s][1], acc[1][1], 0, 0, 0);
    }
#undef LOADH

    // --- epilogue ---
    // C/D 32x32 layout: col = lane&31, row = (reg&3) + 8*(reg>>2) + 4*(lane>>5)
    // ni-fold -> lane^16,^8 folds -> LDS [128][17] -> 128-thread row scan
#pragma unroll
    for (int mi = 0; mi < 2; ++mi) {
#pragma unroll
        for (int reg = 0; reg < 16; ++reg) {
            float best = acc[mi][0][reg];
            int bni = 0;
            if (acc[mi][1][reg] > best) { best = acc[mi][1][reg]; bni = 1; }
            int n = n0 + wc * 64 + bni * 32 + col;
#pragma unroll
            for (int d = 16; d >= 8; d >>= 1) {    // fold cols ^16 then ^8
                float ov = __shfl_xor(best, d, 64);
                int   oi = __shfl_xor(n, d, 64);
                if (ov > best || (ov == best && oi < n)) { best = ov; n = oi; }
            }
            if ((lane & 24) == 0) {
                const int row = wr * 64 + mi * 32 + (reg & 3) + 8 * (reg >> 2) + 4 * hi;
                const int c   = wc * 8 + (lane & 7);
                vals[row * 17 + c] = best;
                idxs[row * 17 + c] = n;
            }
        }
    }
    __syncthreads();
    if (tid < 128) {
        float bv = vals[tid * 17 + 0]; int bi = idxs[tid * 17 + 0];
#pragma unroll
        for (int c = 1; c < 16; ++c) {
            float v = vals[tid * 17 + c]; int ix = idxs[tid * 17 + c];
            if (v > bv || (v == bv && ix < bi)) { bv = v; bi = ix; }
        }
        unsigned vb = __float_as_uint(bv);
        vb = (vb & 0x80000000u) ? ~vb : (vb | 0x80000000u);
        unsigned long long key = ((unsigned long long)vb << 32) | (unsigned)(~bi);
        atomicMax(&keys[m0 + tid], key);
    }
}

// decode keys -> flow + cost
__global__ void finalize_keys_kernel(const unsigned long long* __restrict__ keys,
                                     float* __restrict__ out) {
    int m = blockIdx.x * blockDim.x + threadIdx.x;
    if (m >= M_TOT) return;
    unsigned long long key = keys[m];
    unsigned hi = (unsigned)(key >> 32);
    unsigned bits = (hi & 0x80000000u) ? (hi & 0x7fffffffu) : ~hi;
    float v = __uint_as_float(bits);
    int idx = (int)(~(unsigned)(key & 0xffffffffu));
    int h = m / W_DIM, w = m % W_DIM;
    int i = idx / W_DIM, j = idx % W_DIM;
    out[m * 2 + 0] = (float)(w - SCALE * j);
    out[m * 2 + 1] = (float)(h - SCALE * i);
    out[2 * M_TOT + m] = v;
}

// ---------------------------------------------------------------------------
// Fallback fp32 VALU path in case ws_size is too small.
// ---------------------------------------------------------------------------
#define BM 128
#define BN 128
#define KB 32
__global__ __launch_bounds__(256)
void corr_argmax_kernel(const float* __restrict__ L, const float* __restrict__ R,
                        float* __restrict__ pbest, int* __restrict__ pidx,
                        int nsplit) {
    __shared__ float As[KB][BM];
    __shared__ float Bs[KB][BN];
    const int tid = threadIdx.x;
    const int mtiles = M_TOT / BM;
    const int mt = blockIdx.x % mtiles;
    const int s  = blockIdx.x / mtiles;
    const int m0 = mt * BM;
    const int ns = N_TOT / nsplit;
    const int ntiles = ns / BN;
    const int tx = tid & 15;
    const int ty = tid >> 4;
    float rbest[8]; int ridx[8];
#pragma unroll
    for (int i = 0; i < 8; ++i) { rbest[i] = NEG_INF; ridx[i] = 0; }
    for (int nt = 0; nt < ntiles; ++nt) {
        const int n0 = s * ns + nt * BN;
        float acc[8][8];
#pragma unroll
        for (int i = 0; i < 8; ++i)
#pragma unroll
            for (int j = 0; j < 8; ++j) acc[i][j] = 0.f;
        for (int kb = 0; kb < K_TOT; kb += KB) {
            __syncthreads();
#pragma unroll
            for (int r = 0; r < 4; ++r) {
                int f  = tid + 256 * r;
                int kk = f >> 5;
                int c4 = f & 31;
                float4 va = *reinterpret_cast<const float4*>(&L[(size_t)(kb + kk) * M_TOT + m0 + c4 * 4]);
                *reinterpret_cast<float4*>(&As[kk][c4 * 4]) = va;
                float4 vb = *reinterpret_cast<const float4*>(&R[(size_t)(kb + kk) * N_TOT + n0 + c4 * 4]);
                *reinterpret_cast<float4*>(&Bs[kk][c4 * 4]) = vb;
            }
            __syncthreads();
#pragma unroll 4
            for (int kk = 0; kk < KB; ++kk) {
                float4 a0 = *reinterpret_cast<const float4*>(&As[kk][ty * 4]);
                float4 a1 = *reinterpret_cast<const float4*>(&As[kk][64 + ty * 4]);
                float4 b0 = *reinterpret_cast<const float4*>(&Bs[kk][tx * 4]);
                float4 b1 = *reinterpret_cast<const float4*>(&Bs[kk][64 + tx * 4]);
                float a[8] = {a0.x, a0.y, a0.z, a0.w, a1.x, a1.y, a1.z, a1.w};
                float b[8] = {b0.x, b0.y, b0.z, b0.w, b1.x, b1.y, b1.z, b1.w};
#pragma unroll
                for (int i = 0; i < 8; ++i)
#pragma unroll
                    for (int j = 0; j < 8; ++j)
                        acc[i][j] = fmaf(a[i], b[j], acc[i][j]);
            }
        }
#pragma unroll
        for (int i = 0; i < 8; ++i)
#pragma unroll
            for (int jh = 0; jh < 2; ++jh)
#pragma unroll
                for (int jj = 0; jj < 4; ++jj) {
                    int n = n0 + jh * 64 + tx * 4 + jj;
                    float v = acc[i][jh * 4 + jj];
                    if (v > rbest[i]) { rbest[i] = v; ridx[i] = n; }
                }
    }
    __syncthreads();
    float (*redv)[BM] = reinterpret_cast<float(*)[BM]>(&As[0][0]);
    int   (*redi)[BM] = reinterpret_cast<int  (*)[BM]>(&Bs[0][0]);
#pragma unroll
    for (int i = 0; i < 8; ++i) {
        int row = (i >> 2) * 64 + ty * 4 + (i & 3);
        redv[tx][row] = rbest[i];
        redi[tx][row] = ridx[i];
    }
    __syncthreads();
    if (tid < BM) {
        float bv = NEG_INF; int bi = 0x7fffffff;
        for (int t = 0; t < 16; ++t) {
            float v  = redv[t][tid];
            int   ix = redi[t][tid];
            if (v > bv || (v == bv && ix < bi)) { bv = v; bi = ix; }
        }
        pbest[(size_t)s * M_TOT + m0 + tid] = bv;
        pidx [(size_t)s * M_TOT + m0 + tid] = bi;
    }
}

__global__ void finalize_parts_kernel(const float* __restrict__ pbest,
                                      const int* __restrict__ pidx,
                                      float* __restrict__ out, int nsplit) {
    int m = blockIdx.x * blockDim.x + threadIdx.x;
    if (m >= M_TOT) return;
    float bv = NEG_INF; int bi = 0x7fffffff;
    for (int s = 0; s < nsplit; ++s) {
        float v  = pbest[(size_t)s * M_TOT + m];
        int   ix = pidx [(size_t)s * M_TOT + m];
        if (v > bv || (v == bv && ix < bi)) { bv = v; bi = ix; }
    }
    int h = m / W_DIM, w = m % W_DIM;
    int i = bi / W_DIM, j = bi % W_DIM;
    out[m * 2 + 0] = (float)(w - SCALE * j);
    out[m * 2 + 1] = (float)(h - SCALE * i);
    out[2 * M_TOT + m] = bv;
}

extern "C" void kernel_launch(void* const* d_in, const int* in_sizes, int n_in,
                              void* d_out, int out_size, void* d_ws, size_t ws_size,
                              hipStream_t stream) {
    const float* L = (const float*)d_in[0];
    const float* R = (const float*)d_in[1];
    float* out = (float*)d_out;

    const size_t PKbytes = (size_t)M_TOT * KP * sizeof(_Float16);   // 9.44 MB
    const size_t need = 2 * PKbytes + (size_t)M_TOT * 8;            // ~19 MB
    if (ws_size >= need) {
        _Float16* Ls = (_Float16*)d_ws;
        _Float16* Rs = (_Float16*)((char*)d_ws + PKbytes);
        unsigned long long* keys = (unsigned long long*)((char*)d_ws + 2 * PKbytes);
        split_prep_kernel<<<dim3(432), dim3(256), 0, stream>>>(L, R, Ls, Rs, keys);
        mfma_corr_kernel<<<dim3((M_TOT / 128) * (N_TOT / 128)), dim3(256), 0, stream>>>(Ls, Rs, keys);
        finalize_keys_kernel<<<dim3(48), dim3(256), 0, stream>>>(keys, out);
    } else {
        int nsplit = 8;
        while (nsplit > 1 && (size_t)nsplit * M_TOT * 8 > ws_size) nsplit >>= 1;
        float* pbest = (float*)d_ws;
        int*   pidx  = (int*)((char*)d_ws + (size_t)nsplit * M_TOT * sizeof(float));
        corr_argmax_kernel<<<dim3((M_TOT / BM) * nsplit), dim3(256), 0, stream>>>(L, R, pbest, pidx, nsplit);
        finalize_parts_kernel<<<dim3((M_TOT + 255) / 256), dim3(256), 0, stream>>>(pbest, pidx, out, nsplit);
    }
}

// Round 10
// 235.632 us; speedup vs baseline: 1.1608x; 1.1001x over previous
//
#include <hip/hip_runtime.h>

// Problem constants: B=1, C=128, H=96, W=128
#define K_TOT 128
#define H_DIM 96
#define W_DIM 128
#define M_TOT (H_DIM * W_DIM)   // 12288
#define N_TOT (H_DIM * W_DIM)   // 12288
#define SCALE 4
#define NEG_INF (-3.402823e38f)

#define KP 384                  // folded K' = 3 x 128 sections
#define NH 24                   // K' halves of 16
#define SLAB_F16 24576          // 64 rows x 384 k' f16 per slab

typedef _Float16 f16x8 __attribute__((ext_vector_type(8)));
typedef float f32x16 __attribute__((ext_vector_type(16)));

// ---------------------------------------------------------------------------
// Prep: fp32 [K][P] -> f16 triplet in FRAG-MAJOR layout + fused keys-init.
//  x = h + l/64 with h=f16(x), l=f16((x-hf)*64)  (x-hf exact by Sterbenz)
//  k' sections: L: [h | h/64 | l]   R: [h | l | h/64]
//  => dot = h*h' + h*(y-h') + (x-h)*h'  (drop (x-h)(y-h') ~ 2^-22|xy|)
// Frag-major: slab s (64 rows), chunk c = half*128 + op*64 + hi*32 + col
// (half=k'/16, op=32-row half, hi=k-half, col=row%32): 8 f16 at
// dst[s*24576 + c*8] = exactly lane (hi*32+col)'s MFMA operand bytes.
// A wave's frag load is then one coalesced 1024B global_load_dwordx4 sweep.
// ---------------------------------------------------------------------------
__global__ __launch_bounds__(256)
void split_prep_kernel(const float* __restrict__ L, const float* __restrict__ R,
                       _Float16* __restrict__ Ls, _Float16* __restrict__ Rs,
                       unsigned long long* __restrict__ keys) {
    const int t = threadIdx.x;
    if (blockIdx.x >= 384) {            // fused keys init (48 blocks)
        int m = (blockIdx.x - 384) * 256 + t;
        if (m < M_TOT) keys[m] = 0ull;
        return;
    }
    __shared__ __align__(16) _Float16 T[3][64][144];   // planes: 0=h, 1=l, 2=h/64
    const int isR  = blockIdx.x >= 192;
    const int slab = blockIdx.x - (isR ? 192 : 0);     // 0..191
    const int P0   = slab * 64;
    const float* src = isR ? R : L;
    _Float16* dst = isR ? Rs : Ls;

    const int p4 = (t & 15) * 4;
    const int k0 = t >> 4;
#pragma unroll
    for (int it = 0; it < 8; ++it) {
        const int k = k0 + it * 16;
        float4 v = *(const float4*)&src[(size_t)k * M_TOT + P0 + p4];
        float xs[4] = {v.x, v.y, v.z, v.w};
#pragma unroll
        for (int j = 0; j < 4; ++j) {
            _Float16 h = (_Float16)xs[j];
            float hf = (float)h;
            float r = xs[j] - hf;                    // exact
            T[0][p4 + j][k] = h;
            T[1][p4 + j][k] = (_Float16)(r * 64.0f);
            T[2][p4 + j][k] = (_Float16)(hf * 0.015625f);  // h/64 (exact exp shift)
        }
    }
    __syncthreads();
    // 3072 16B-chunks per slab: c = half*128 + op*64 + hi*32 + col
#pragma unroll
    for (int it = 0; it < 12; ++it) {
        const int c    = it * 256 + t;
        const int col  = c & 31;
        const int hi   = (c >> 5) & 1;
        const int op   = (c >> 6) & 1;
        const int half = c >> 7;             // 0..23
        const int sec  = half >> 3;          // 0,1,2
        const int kb   = (half & 7) * 16 + hi * 8;
        const int plane = (sec == 0) ? 0 : (isR ? sec : 3 - sec);
        const int row  = op * 32 + col;
        float4 v = *(const float4*)&T[plane][row][kb];
        *(float4*)&dst[(size_t)slab * SLAB_F16 + (size_t)c * 8] = v;
    }
}

// ---------------------------------------------------------------------------
// Main: 128x128 tile, 4 waves (2x2), wave-tile 64x64, mfma_f32_32x32x16_f16.
// NO LDS / NO barriers in the K loop: fragments load directly global->VGPR
// from the frag-major workspace (coalesced 1024B per wave-frag), register
// triple-buffer with depth-2 prefetch (static %3 indices under full unroll);
// the compiler inserts the counted vmcnt before first use. Reuse lives in
// L2: XCD supertile keeps each XCD's 1.15 MB B slice resident.
// 16 waves/CU (launch_bounds(256,4)): 56 VGPR + 64 AGPR = 120 <= 128/wave at
// 4 waves/SIMD -- fits without spill; independent blocks overlap freely
// (m114 regime), attacking the ~780cyc loaded-L2 latency that bounds r9.
// setprio(1) around the MFMA quad: waves are at independent phases (m191
// regime where setprio pays, unlike barrier-locked GEMM m190).
// ---------------------------------------------------------------------------
__global__ __launch_bounds__(256, 4)
void mfma_corr_kernel(const _Float16* __restrict__ Ls, const _Float16* __restrict__ Rs,
                      unsigned long long* __restrict__ keys) {
    __shared__ float vals[128 * 17];
    __shared__ int   idxs[128 * 17];

    const int tid  = threadIdx.x;
    const int lane = tid & 63;
    const int wid  = tid >> 6;      // 0..3
    const int wr   = wid >> 1;      // 0..1 : M 64-row slab
    const int wc   = wid & 1;       // 0..1 : N 64-col slab
    const int col  = lane & 31;
    const int hi   = lane >> 5;
    // supertile: 9216 = 8 XCDs x (96 mt x 12 nt_local); bijective
    const int bid  = blockIdx.x;
    const int xcd  = bid & 7;
    const int b    = bid >> 3;              // 0..1151
    const int mt   = b / 12;                // 0..95 (slow)
    const int nt   = xcd * 12 + b % 12;     // 0..95 (XCD-local slice)
    const int m0   = mt * 128;
    const int n0   = nt * 128;

    const _Float16* pA = Ls + (size_t)(mt * 2 + wr) * SLAB_F16 + lane * 8;
    const _Float16* pB = Rs + (size_t)(nt * 2 + wc) * SLAB_F16 + lane * 8;

    f32x16 acc[2][2];
#pragma unroll
    for (int mi = 0; mi < 2; ++mi)
#pragma unroll
        for (int ni = 0; ni < 2; ++ni) acc[mi][ni] = (f32x16)(0.0f);

    f16x8 fA[3][2], fB[3][2];
#define LOADH(hh, s) {                                              \
        fA[s][0] = *(const f16x8*)(pA + (hh) * 1024);               \
        fA[s][1] = *(const f16x8*)(pA + (hh) * 1024 + 512);         \
        fB[s][0] = *(const f16x8*)(pB + (hh) * 1024);               \
        fB[s][1] = *(const f16x8*)(pB + (hh) * 1024 + 512);         \
    }
    LOADH(0, 0);
    LOADH(1, 1);
#pragma unroll
    for (int h = 0; h < NH; ++h) {
        if (h + 2 < NH) LOADH(h + 2, (h + 2) % 3);      // depth-2 prefetch
        const int s = h % 3;                             // static under unroll
        __builtin_amdgcn_s_setprio(1);
        acc[0][0] = __builtin_amdgcn_mfma_f32_32x32x16_f16(fA[s][0], fB[s][0], acc[0][0], 0, 0, 0);
        acc[0][1] = __builtin_amdgcn_mfma_f32_32x32x16_f16(fA[s][0], fB[s][1], acc[0][1], 0, 0, 0);
        acc[1][0] = __builtin_amdgcn_mfma_f32_32x32x16_f16(fA[s][1], fB[s][0], acc[1][0], 0, 0, 0);
        acc[1][1] = __builtin_amdgcn_mfma_f32_32x32x16_f16(fA[s][1], fB[s][1], acc[1][1], 0, 0, 0);
        __builtin_amdgcn_s_setprio(0);
    }
#undef LOADH

    // --- epilogue ---
    // C/D 32x32 layout: col = lane&31, row = (reg&3) + 8*(reg>>2) + 4*(lane>>5)
    // ni-fold -> lane^16,^8 folds -> LDS [128][17] -> 128-thread row scan
#pragma unroll
    for (int mi = 0; mi < 2; ++mi) {
#pragma unroll
        for (int reg = 0; reg < 16; ++reg) {
            float best = acc[mi][0][reg];
            int bni = 0;
            if (acc[mi][1][reg] > best) { best = acc[mi][1][reg]; bni = 1; }
            int n = n0 + wc * 64 + bni * 32 + col;
#pragma unroll
            for (int d = 16; d >= 8; d >>= 1) {    // fold cols ^16 then ^8
                float ov = __shfl_xor(best, d, 64);
                int   oi = __shfl_xor(n, d, 64);
                if (ov > best || (ov == best && oi < n)) { best = ov; n = oi; }
            }
            if ((lane & 24) == 0) {
                const int row = wr * 64 + mi * 32 + (reg & 3) + 8 * (reg >> 2) + 4 * hi;
                const int c   = wc * 8 + (lane & 7);
                vals[row * 17 + c] = best;
                idxs[row * 17 + c] = n;
            }
        }
    }
    __syncthreads();
    if (tid < 128) {
        float bv = vals[tid * 17 + 0]; int bi = idxs[tid * 17 + 0];
#pragma unroll
        for (int c = 1; c < 16; ++c) {
            float v = vals[tid * 17 + c]; int ix = idxs[tid * 17 + c];
            if (v > bv || (v == bv && ix < bi)) { bv = v; bi = ix; }
        }
        unsigned vb = __float_as_uint(bv);
        vb = (vb & 0x80000000u) ? ~vb : (vb | 0x80000000u);
        unsigned long long key = ((unsigned long long)vb << 32) | (unsigned)(~bi);
        atomicMax(&keys[m0 + tid], key);
    }
}

// decode keys -> flow + cost
__global__ void finalize_keys_kernel(const unsigned long long* __restrict__ keys,
                                     float* __restrict__ out) {
    int m = blockIdx.x * blockDim.x + threadIdx.x;
    if (m >= M_TOT) return;
    unsigned long long key = keys[m];
    unsigned hi = (unsigned)(key >> 32);
    unsigned bits = (hi & 0x80000000u) ? (hi & 0x7fffffffu) : ~hi;
    float v = __uint_as_float(bits);
    int idx = (int)(~(unsigned)(key & 0xffffffffu));
    int h = m / W_DIM, w = m % W_DIM;
    int i = idx / W_DIM, j = idx % W_DIM;
    out[m * 2 + 0] = (float)(w - SCALE * j);
    out[m * 2 + 1] = (float)(h - SCALE * i);
    out[2 * M_TOT + m] = v;
}

// ---------------------------------------------------------------------------
// Fallback fp32 VALU path in case ws_size is too small.
// ---------------------------------------------------------------------------
#define BM 128
#define BN 128
#define KB 32
__global__ __launch_bounds__(256)
void corr_argmax_kernel(const float* __restrict__ L, const float* __restrict__ R,
                        float* __restrict__ pbest, int* __restrict__ pidx,
                        int nsplit) {
    __shared__ float As[KB][BM];
    __shared__ float Bs[KB][BN];
    const int tid = threadIdx.x;
    const int mtiles = M_TOT / BM;
    const int mt = blockIdx.x % mtiles;
    const int s  = blockIdx.x / mtiles;
    const int m0 = mt * BM;
    const int ns = N_TOT / nsplit;
    const int ntiles = ns / BN;
    const int tx = tid & 15;
    const int ty = tid >> 4;
    float rbest[8]; int ridx[8];
#pragma unroll
    for (int i = 0; i < 8; ++i) { rbest[i] = NEG_INF; ridx[i] = 0; }
    for (int nt = 0; nt < ntiles; ++nt) {
        const int n0 = s * ns + nt * BN;
        float acc[8][8];
#pragma unroll
        for (int i = 0; i < 8; ++i)
#pragma unroll
            for (int j = 0; j < 8; ++j) acc[i][j] = 0.f;
        for (int kb = 0; kb < K_TOT; kb += KB) {
            __syncthreads();
#pragma unroll
            for (int r = 0; r < 4; ++r) {
                int f  = tid + 256 * r;
                int kk = f >> 5;
                int c4 = f & 31;
                float4 va = *reinterpret_cast<const float4*>(&L[(size_t)(kb + kk) * M_TOT + m0 + c4 * 4]);
                *reinterpret_cast<float4*>(&As[kk][c4 * 4]) = va;
                float4 vb = *reinterpret_cast<const float4*>(&R[(size_t)(kb + kk) * N_TOT + n0 + c4 * 4]);
                *reinterpret_cast<float4*>(&Bs[kk][c4 * 4]) = vb;
            }
            __syncthreads();
#pragma unroll 4
            for (int kk = 0; kk < KB; ++kk) {
                float4 a0 = *reinterpret_cast<const float4*>(&As[kk][ty * 4]);
                float4 a1 = *reinterpret_cast<const float4*>(&As[kk][64 + ty * 4]);
                float4 b0 = *reinterpret_cast<const float4*>(&Bs[kk][tx * 4]);
                float4 b1 = *reinterpret_cast<const float4*>(&Bs[kk][64 + tx * 4]);
                float a[8] = {a0.x, a0.y, a0.z, a0.w, a1.x, a1.y, a1.z, a1.w};
                float b[8] = {b0.x, b0.y, b0.z, b0.w, b1.x, b1.y, b1.z, b1.w};
#pragma unroll
                for (int i = 0; i < 8; ++i)
#pragma unroll
                    for (int j = 0; j < 8; ++j)
                        acc[i][j] = fmaf(a[i], b[j], acc[i][j]);
            }
        }
#pragma unroll
        for (int i = 0; i < 8; ++i)
#pragma unroll
            for (int jh = 0; jh < 2; ++jh)
#pragma unroll
                for (int jj = 0; jj < 4; ++jj) {
                    int n = n0 + jh * 64 + tx * 4 + jj;
                    float v = acc[i][jh * 4 + jj];
                    if (v > rbest[i]) { rbest[i] = v; ridx[i] = n; }
                }
    }
    __syncthreads();
    float (*redv)[BM] = reinterpret_cast<float(*)[BM]>(&As[0][0]);
    int   (*redi)[BM] = reinterpret_cast<int  (*)[BM]>(&Bs[0][0]);
#pragma unroll
    for (int i = 0; i < 8; ++i) {
        int row = (i >> 2) * 64 + ty * 4 + (i & 3);
        redv[tx][row] = rbest[i];
        redi[tx][row] = ridx[i];
    }
    __syncthreads();
    if (tid < BM) {
        float bv = NEG_INF; int bi = 0x7fffffff;
        for (int t = 0; t < 16; ++t) {
            float v  = redv[t][tid];
            int   ix = redi[t][tid];
            if (v > bv || (v == bv && ix < bi)) { bv = v; bi = ix; }
        }
        pbest[(size_t)s * M_TOT + m0 + tid] = bv;
        pidx [(size_t)s * M_TOT + m0 + tid] = bi;
    }
}

__global__ void finalize_parts_kernel(const float* __restrict__ pbest,
                                      const int* __restrict__ pidx,
                                      float* __restrict__ out, int nsplit) {
    int m = blockIdx.x * blockDim.x + threadIdx.x;
    if (m >= M_TOT) return;
    float bv = NEG_INF; int bi = 0x7fffffff;
    for (int s = 0; s < nsplit; ++s) {
        float v  = pbest[(size_t)s * M_TOT + m];
        int   ix = pidx [(size_t)s * M_TOT + m];
        if (v > bv || (v == bv && ix < bi)) { bv = v; bi = ix; }
    }
    int h = m / W_DIM, w = m % W_DIM;
    int i = bi / W_DIM, j = bi % W_DIM;
    out[m * 2 + 0] = (float)(w - SCALE * j);
    out[m * 2 + 1] = (float)(h - SCALE * i);
    out[2 * M_TOT + m] = bv;
}

extern "C" void kernel_launch(void* const* d_in, const int* in_sizes, int n_in,
                              void* d_out, int out_size, void* d_ws, size_t ws_size,
                              hipStream_t stream) {
    const float* L = (const float*)d_in[0];
    const float* R = (const float*)d_in[1];
    float* out = (float*)d_out;

    const size_t PKbytes = (size_t)M_TOT * KP * sizeof(_Float16);   // 9.44 MB
    const size_t need = 2 * PKbytes + (size_t)M_TOT * 8;            // ~19 MB
    if (ws_size >= need) {
        _Float16* Ls = (_Float16*)d_ws;
        _Float16* Rs = (_Float16*)((char*)d_ws + PKbytes);
        unsigned long long* keys = (unsigned long long*)((char*)d_ws + 2 * PKbytes);
        split_prep_kernel<<<dim3(432), dim3(256), 0, stream>>>(L, R, Ls, Rs, keys);
        mfma_corr_kernel<<<dim3((M_TOT / 128) * (N_TOT / 128)), dim3(256), 0, stream>>>(Ls, Rs, keys);
        finalize_keys_kernel<<<dim3(48), dim3(256), 0, stream>>>(keys, out);
    } else {
        int nsplit = 8;
        while (nsplit > 1 && (size_t)nsplit * M_TOT * 8 > ws_size) nsplit >>= 1;
        float* pbest = (float*)d_ws;
        int*   pidx  = (int*)((char*)d_ws + (size_t)nsplit * M_TOT * sizeof(float));
        corr_argmax_kernel<<<dim3((M_TOT / BM) * nsplit), dim3(256), 0, stream>>>(L, R, pbest, pidx, nsplit);
        finalize_parts_kernel<<<dim3((M_TOT + 255) / 256), dim3(256), 0, stream>>>(pbest, pidx, out, nsplit);
    }
}